// Round 7
// baseline (277.038 us; speedup 1.0000x reference)
//
#include <hip/hip_runtime.h>

// MultiCamNoiseCropV3Prompter: out = x + prompt broadcast over T frames.
// R9: grid-stride ILP=4 over the SAME linear front as R8.
// Evidence ladder: NT stores (R7), occupancy (R6), front shape (R8) all
// exonerated; every fused variant sits at 3.6-4.3 TB/s effective while the
// rocclr fills do 6.7 TB/s on the same buffers at 9.7% occupancy. The fills
// are grid-stride loops (many wide memory ops per wave); R8 waves issue ONE
// load+store each, diluting request rate with per-wave fixed overhead (T1:
// issue-density bound). R9: stride = TOTAL/4 f4 = 38.5 MB advances exactly
// b+=4 (c,t,i,j fixed) -> decode ONCE, 4 loads in flight per thread, front
// stays a contiguous 38.5 MB sweep. 9408 blocks; b block-uniform per iter.
// Predict: kernel 85 -> 55-65 us (total ~240-250); if unchanged, conclude
// practical mixed-stream ceiling reached.

#define PP 30
#define SS 224
#define CROPC 164
#define BB 16
#define TT 16
#define ITER 4

// float4 elements in the whole tensor and per b-quarter (4 b's each).
#define TOTAL_F4 (BB * 3 * TT * SS * (SS / 4))          // 9,633,792
#define QUARTER_F4 (TOTAL_F4 / ITER)                     // 2,408,448 = +4 in b

typedef float f4 __attribute__((ext_vector_type(4)));

__device__ __forceinline__ void interp1d(float pos, float in_size, int in_size_i,
                                         int out_size, int& i0, int& i1, float& w) {
    float scale = in_size / (float)out_size;
    float f = fmaxf((pos + 0.5f) * scale - 0.5f, 0.0f);
    i0 = (int)floorf(f);
    w = f - (float)i0;
    i1 = min(i0 + 1, in_size_i - 1);
}

__device__ __forceinline__ void prompt_quad(
        const float* __restrict__ pu, const float* __restrict__ pd,
        const float* __restrict__ pl, const float* __restrict__ pr,
        int cam, int off_r, int off_d, int c, int i, int j0, float pv[4]) {
    const int off_l = 2 * PP - off_r;
    const int off_u = 2 * PP - off_d;
    const float* puc = pu + (size_t)(cam * 3 + c) * (2 * PP) * SS;
    const float* pdc = pd + (size_t)(cam * 3 + c) * PP * SS;
    const float* plc = pl + (size_t)(cam * 3 + c) * CROPC * (2 * PP);
    const float* prc = pr + (size_t)(cam * 3 + c) * CROPC * PP;

    if (i < off_u) {
        int r0, r1; float w;
        interp1d((float)i, (float)(2 * PP), 2 * PP, off_u, r0, r1, w);
        const float* a  = puc + (size_t)r0 * SS + j0;
        const float* bp = puc + (size_t)r1 * SS + j0;
        #pragma unroll
        for (int k = 0; k < 4; k++)
            pv[k] = a[k] * (1.0f - w) + bp[k] * w;
    } else if (i >= SS - off_d) {
        int r0, r1; float w;
        interp1d((float)(i - (SS - off_d)), (float)PP, PP, off_d, r0, r1, w);
        const float* a  = pdc + (size_t)r0 * SS + j0;
        const float* bp = pdc + (size_t)r1 * SS + j0;
        #pragma unroll
        for (int k = 0; k < 4; k++)
            pv[k] = a[k] * (1.0f - w) + bp[k] * w;
    } else {
        const int r = i - off_u;
        const float* plr = plc + (size_t)r * (2 * PP);
        const float* prr = prc + (size_t)r * PP;
        #pragma unroll
        for (int k = 0; k < 4; k++) {
            int j = j0 + k;
            float v = 0.0f;
            if (j < off_l) {
                int c0, c1; float w;
                interp1d((float)j, (float)(2 * PP), 2 * PP, off_l, c0, c1, w);
                v = plr[c0] * (1.0f - w) + plr[c1] * w;
            } else if (j >= SS - off_r) {
                int c0, c1; float w;
                interp1d((float)(j - (SS - off_r)), (float)PP, PP, off_r, c0, c1, w);
                v = prr[c0] * (1.0f - w) + prr[c1] * w;
            }
            pv[k] = v;
        }
    }
}

__global__ void __launch_bounds__(256)
fused_gs_kernel(const float* __restrict__ x,
                const float* __restrict__ pu,   // [3,3,2P,S]
                const float* __restrict__ pd,   // [3,3,P,S]
                const float* __restrict__ pl,   // [3,3,CROP,2P]
                const float* __restrict__ pr,   // [3,3,CROP,P]
                const int* __restrict__ cam_views,
                const int* __restrict__ offs_r,
                const int* __restrict__ offs_d,
                float* __restrict__ out) {
    const int J4 = SS / 4;  // 56
    int idx = blockIdx.x * blockDim.x + threadIdx.x;  // [0, QUARTER_F4)
    // Layout: g = (((b*3+c)*TT + t)*SS + i)*J4 + j4.
    // g + k*QUARTER_F4 advances b by 4k with c,t,i,j4 unchanged.

    // ---- issue all 4 streaming loads FIRST (4 KB in flight per thread).
    f4 xv[ITER];
    #pragma unroll
    for (int k = 0; k < ITER; k++)
        xv[k] = *reinterpret_cast<const f4*>(
            x + ((size_t)idx + (size_t)k * QUARTER_F4) * 4);

    // ---- decode ONCE.
    int j4 = idx % J4;
    int tmp = idx / J4;
    int i = tmp % SS;
    tmp /= SS;            // tmp = (b0*3 + c)*TT + t, b0 in [0,4)
    int bc = tmp / TT;
    int c = bc % 3;
    int b0 = bc / 3;      // block-uniform: 2352 whole blocks per b0
    const int j0 = j4 * 4;

    // ---- per-iteration: params are scalar (b uniform per block per iter).
    #pragma unroll
    for (int k = 0; k < ITER; k++) {
        const int bu = __builtin_amdgcn_readfirstlane(b0) + 4 * k;
        const int cam   = cam_views[bu];
        const int off_r = offs_r[bu];
        const int off_d = offs_d[bu];

        float pv[4];
        prompt_quad(pu, pd, pl, pr, cam, off_r, off_d, c, i, j0, pv);

        f4 ov = xv[k];
        ov[0] += pv[0];
        ov[1] += pv[1];
        ov[2] += pv[2];
        ov[3] += pv[3];
        *reinterpret_cast<f4*>(
            out + ((size_t)idx + (size_t)k * QUARTER_F4) * 4) = ov;
    }
}

extern "C" void kernel_launch(void* const* d_in, const int* in_sizes, int n_in,
                              void* d_out, int out_size, void* d_ws, size_t ws_size,
                              hipStream_t stream) {
    const float* x  = (const float*)d_in[0];
    const float* pu = (const float*)d_in[1];
    const float* pd = (const float*)d_in[2];
    const float* pl = (const float*)d_in[3];
    const float* pr = (const float*)d_in[4];
    const int* cam  = (const int*)d_in[5];
    const int* orr  = (const int*)d_in[6];
    const int* od   = (const int*)d_in[7];
    float* out = (float*)d_out;

    // QUARTER_F4 threads, 1 float4 x ITER=4 strided-by-quarter each.
    fused_gs_kernel<<<QUARTER_F4 / 256, 256, 0, stream>>>(
        x, pu, pd, pl, pr, cam, orr, od, out);
}